// Round 10
// baseline (142.053 us; speedup 1.0000x reference)
//
#include <hip/hip_runtime.h>
#include <stdint.h>

#define HW 262144            // 512*512
#define ACQ_N 2097152        // 8*1*512*512
#define SREG 69632           // slots per class region = 65536 + 4096 slack (18 sigma)
#define NREG3 208896         // 3*SREG slots per batch (classes 1..3)

// each (batch,class) counter on its OWN 128-byte line (R3 post-mortem: all
// atomics on one line serialized the whole scatter kernel)
#define CNT(b, c) ((((b) << 2) | (c)) << 5)

// hw-native transcendentals (1 instr each)
#define LOG2F(x) __builtin_amdgcn_logf(x)
#define EXP2F(x) __builtin_amdgcn_exp2f(x)
#define SQRTF(x) __builtin_amdgcn_sqrtf(x)
#define RCPF(x)  __builtin_amdgcn_rcpf(x)

#define ROTL(x, r) __builtin_amdgcn_alignbit((x), (x), (32 - (r)) & 31)

// ---------- host-side threefry2x32 for key derivation ----------
static inline void tf2x32_host(uint32_t k0, uint32_t k1, uint32_t c0, uint32_t c1,
                               uint32_t& o0, uint32_t& o1) {
  const uint32_t ks2 = k0 ^ k1 ^ 0x1BD11BDAu;
  uint32_t x0 = c0 + k0, x1 = c1 + k1;
#define TFR(r) { x0 += x1; x1 = (x1 << (r)) | (x1 >> (32 - (r))); x1 ^= x0; }
  TFR(13) TFR(15) TFR(26) TFR(6)
  x0 += k1;  x1 += ks2 + 1u;
  TFR(17) TFR(29) TFR(16) TFR(24)
  x0 += ks2; x1 += k0 + 2u;
  TFR(13) TFR(15) TFR(26) TFR(6)
  x0 += k0;  x1 += k1 + 3u;
  TFR(17) TFR(29) TFR(16) TFR(24)
  x0 += k1;  x1 += ks2 + 4u;
  TFR(13) TFR(15) TFR(26) TFR(6)
  x0 += ks2; x1 += k0 + 5u;
#undef TFR
  o0 = x0; o1 = x1;
}

// device: partitionable random_bits(32) for counter (0, idx): o0^o1
__device__ __forceinline__ uint32_t rbits32(uint32_t k0, uint32_t k1, uint32_t idx) {
  const uint32_t ks2 = k0 ^ k1 ^ 0x1BD11BDAu;
  uint32_t x0 = k0, x1 = idx + k1;
#define TFR(r) { x0 += x1; x1 = ROTL(x1, r); x1 ^= x0; }
  TFR(13) TFR(15) TFR(26) TFR(6)
  x0 += k1;  x1 += ks2 + 1u;
  TFR(17) TFR(29) TFR(16) TFR(24)
  x0 += ks2; x1 += k0 + 2u;
  TFR(13) TFR(15) TFR(26) TFR(6)
  x0 += k0;  x1 += k1 + 3u;
  TFR(17) TFR(29) TFR(16) TFR(24)
  x0 += k1;  x1 += ks2 + 4u;
  TFR(13) TFR(15) TFR(26) TFR(6)
  x0 += ks2; x1 += k0 + 5u;
#undef TFR
  return x0 ^ x1;
}

__device__ __forceinline__ float unit_from_bits(uint32_t b) {
  return __uint_as_float((b >> 9) | 0x3F800000u) - 1.0f;
}

// z = sqrt(2)*erfinv(x), Giles poly pre-scaled by sqrt(2); far branch real-branched.
__device__ __forceinline__ float sqrt2_erfinv(float x) {
  float ome = fmaf(-x, x, 1.0f);
  float w = -0.69314718056f * LOG2F(ome);
  float wn = w - 2.5f;
  float p = 3.974065e-08f;
  p = fmaf(p, wn, 4.854641e-07f);
  p = fmaf(p, wn, -4.982823e-06f);
  p = fmaf(p, wn, -6.210531e-06f);
  p = fmaf(p, wn, 3.091200e-04f);
  p = fmaf(p, wn, -1.773035e-03f);
  p = fmaf(p, wn, -5.908135e-03f);
  p = fmaf(p, wn, 3.488029e-01f);
  p = fmaf(p, wn, 2.123314e+00f);
  if (__builtin_expect(w >= 5.0f, 0)) {
    float wf = SQRTF(w) - 3.0f;
    float q = -2.831458e-04f;
    q = fmaf(q, wf, 1.427657e-04f);
    q = fmaf(q, wf, 1.908260e-03f);
    q = fmaf(q, wf, -5.195013e-03f);
    q = fmaf(q, wf, 8.116892e-03f);
    q = fmaf(q, wf, -1.0779791e-02f);
    q = fmaf(q, wf, 1.3348579e-02f);
    q = fmaf(q, wf, 1.416582e+00f);
    q = fmaf(q, wf, 4.006434e+00f);
    p = q;
  }
  return p * x;
}

// ---------- 1-pixel loop (plain-tier fallback) ----------
__device__ __forceinline__ float loop_fg(float base, float fw, float fa, float gw,
                                         uint32_t idx, int nf,
                                         uint32_t ku0, uint32_t ku1,
                                         uint32_t kn0, uint32_t kn1) {
  float nfa = -fa, fac = fa * 0.52876637294f;
  float acc = 0.0f;
#pragma unroll 2
  for (int f = 0; f < nf; ++f) {
    uint32_t ub = rbits32(ku0, ku1, idx);
    uint32_t nb = rbits32(kn0, kn1, idx);
    idx += (uint32_t)HW;
    float u = fminf(fmaxf(unit_from_bits(ub), 1e-6f), 0.999999f);
    float pw = EXP2F(fmaf(nfa, LOG2F(-LOG2F(u)), fac));
    float z = sqrt2_erfinv(fmaf(unit_from_bits(nb), 2.0f, -0.99999994f));
    float t = fmaf(gw, z, fmaf(fw, pw, base));
    acc += fminf(fmaxf(t, 0.0f), 1.0f);
  }
  return acc * RCPF((float)nf);
}

// ================= compacted path (R10: slot-map only) =============
// ws: float partial[512] @0 ; float biasv[8] @2048 ; u32 counters[1024] @4096
//     (padded lines) ; u32 remarr[8][NREG3] @8192
// R10: drop the packed float4 materialization entirely. R6 proved acquire's
// time is INSENSITIVE to scattered input gathers (L2/L3-resident; +4MB FETCH,
// 0 time delta), while scatter's ~50us (residual arithmetic R4/R5/R9) is
// dominated by its scattered 20B/px stores. Scatter now emits only the 4B/px
// slot->pixel map; acquire gathers the needed channels directly from inp[rem]
// and recomputes base = img[rem] + biasv[b]. Pipeline traffic -40MB.

// phase 1: per-(batch,chunk) bias partials; block 0 zeros the class counters.
__global__ __launch_bounds__(256) void bias_partial(const float* __restrict__ inp,
                                                    float* __restrict__ partial,
                                                    uint32_t* __restrict__ counters) {
  if (blockIdx.x == 0) {
    counters[threadIdx.x] = 0u;
    counters[256 + threadIdx.x] = 0u;
    counters[512 + threadIdx.x] = 0u;
    counters[768 + threadIdx.x] = 0u;
  }
  int blk = blockIdx.x;
  int b = blk >> 6, chunk = blk & 63;
  const float4* src = (const float4*)(inp + ((size_t)b * 5 + 1) * HW
                                          + (size_t)chunk * 4096);
  int t = threadIdx.x;
  float s = 0.0f;
#pragma unroll
  for (int k = 0; k < 4; ++k) {
    float4 v = src[t + k * 256];
    s += (v.x + v.y) + (v.z + v.w);
  }
  for (int off = 32; off; off >>= 1) s += __shfl_down(s, off);
  __shared__ float ws4[4];
  if ((t & 63) == 0) ws4[t >> 6] = s;
  __syncthreads();
  if (t == 0) partial[blk] = ws4[0] + ws4[1] + ws4[2] + ws4[3];
}

// phase 2 (R10): classify + block-aggregated atomic region allocation (R4) +
// remarr-only scatter (4B/px). Also emits center plane, class-0 acquired, and
// persists biasv[b] for acquire.
__global__ __launch_bounds__(256) void scatter_pack(const float* __restrict__ inp,
                                                    const float* __restrict__ partial,
                                                    float* __restrict__ biasv,
                                                    uint32_t* __restrict__ counters,
                                                    uint32_t* __restrict__ remarr,
                                                    float* __restrict__ out) {
  int blk = blockIdx.x;                 // 2048 blocks: 8 batches x 256 subchunks
  int b = blk >> 8, sub = blk & 255;
  int tid = threadIdx.x, lane = tid & 63, wid = tid >> 6;
  const float* pb = inp + (size_t)b * 5 * HW;
  uint64_t below = (1ull << lane) - 1ull;
  int base_i = sub << 10;

  __shared__ float s_bias;
  __shared__ uint32_t swcnt[4][4];       // [wave][class]
  __shared__ uint32_t sbase[4];          // block's region base per class

  // bias finalize (wave 0); sub==0 block persists biasv[b]
  if (tid < 64) {
    float s = partial[(b << 6) | tid];
    for (int o = 32; o; o >>= 1) s += __shfl_down(s, o);
    if (tid == 0) {
      float bv = fmaxf(s * (1.0f / 262144.0f), 0.0f);
      s_bias = bv;
      if (sub == 0) biasv[b] = bv;
    }
  }

  // prephase: load 4 channels x 4 slices into regs, classify, count per wave
  float img4[4], fw4[4], fa4[4], gw4[4];
  uint32_t cls4[4];
  uint32_t wc1 = 0, wc2 = 0, wc3 = 0;
#pragma unroll
  for (int k = 0; k < 4; ++k) {
    int i = base_i + (k << 8) + tid;
    img4[k]  = pb[i];
    float f2 = pb[2 * HW + i];
    float f3 = pb[3 * HW + i];
    float f4 = pb[4 * HW + i];
    fw4[k] = fmaxf(f2, 0.0f);
    fa4[k] = fmaxf(f3, 0.0f);
    gw4[k] = fmaxf(f4, 0.0f);
    uint32_t cls = (f2 > 0.0f ? 1u : 0u) | (f4 > 0.0f ? 2u : 0u);
    cls4[k] = cls;
    wc1 += (uint32_t)__popcll(__ballot(cls == 1u));
    wc2 += (uint32_t)__popcll(__ballot(cls == 2u));
    wc3 += (uint32_t)__popcll(__ballot(cls == 3u));
  }
  if (lane == 0) {
    swcnt[wid][1] = wc1; swcnt[wid][2] = wc2; swcnt[wid][3] = wc3;
  }
  __syncthreads();
  // 3 atomics per BLOCK, each counter on its own 128B line
  if (tid < 3) {
    int c = tid + 1;
    uint32_t tot = swcnt[0][c] + swcnt[1][c] + swcnt[2][c] + swcnt[3][c];
    sbase[c] = atomicAdd(&counters[CNT(b, c)], tot);
  }
  __syncthreads();

  uint32_t run1 = sbase[1], run2 = sbase[2], run3 = sbase[3];
#pragma unroll
  for (int w = 0; w < 4; ++w) {
    if (w < wid) { run1 += swcnt[w][1]; run2 += swcnt[w][2]; run3 += swcnt[w][3]; }
  }
  float bias = s_bias;

  uint32_t* rbase = remarr + (size_t)b * NREG3;
  float*    outa  = out + (size_t)b * HW;
  float*    outc  = out + ACQ_N + (size_t)b * HW;

#pragma unroll
  for (int k = 0; k < 4; ++k) {
    int i = base_i + (k << 8) + tid;
    float fw = fw4[k], fa = fa4[k];
    float basev = img4[k] + bias;
    // center = clip(base + fw*(1/(fa+1))^fa, 0, 1)  (coalesced write)
    float cpw = EXP2F(-fa * LOG2F(fa + 1.0f));
    float ctr = fminf(fmaxf(fmaf(fw, cpw, basev), 0.0f), 1.0f);
    outc[i] = ctr;

    uint32_t cls = cls4[k];
    if (cls == 0u) outa[i] = ctr;        // fw==0 && gw==0: acquired == center

    uint64_t ba1 = __ballot(cls == 1u);
    uint64_t ba2 = __ballot(cls == 2u);
    uint64_t ba3 = __ballot(cls == 3u);
    if (cls != 0u) {
      uint64_t own  = (cls == 1u) ? ba1 : ((cls == 2u) ? ba2 : ba3);
      uint32_t rbas = (cls == 1u) ? run1 : ((cls == 2u) ? run2 : run3);
      uint32_t roff = (cls - 1u) * (uint32_t)SREG + rbas + (uint32_t)__popcll(own & below);
      rbase[roff] = (uint32_t)i;         // the ONLY scattered store (4B/px)
    }
    run1 += (uint32_t)__popcll(ba1);
    run2 += (uint32_t)__popcll(ba2);
    run3 += (uint32_t)__popcll(ba3);
  }
}

// phase 3 (R10): R9's proven config (2 px/thread, grid (136,8,3) globally
// class-major, class-3 first) but operands GATHERED from inp at rem instead of
// a packed array (R6 evidence: scattered input reads are L2/L3-served, free).
__global__ __launch_bounds__(256) void acquire_packed(
    const float* __restrict__ inp, const int* __restrict__ frames,
    const float* __restrict__ biasv, const uint32_t* __restrict__ counters,
    const uint32_t* __restrict__ remarr, float* __restrict__ out,
    uint32_t ku0, uint32_t ku1, uint32_t kn0, uint32_t kn1) {
  int c = 3 - (int)blockIdx.z;                 // class 3, 2, 1 (heavy first globally)
  int b = (int)blockIdx.y;
  uint32_t cnt = counters[CNT(b, c)];
  uint32_t bslot = (uint32_t)blockIdx.x << 9;  // 512 px/block
  if (bslot >= cnt) return;                    // whole block past region end
  int nf = frames[b];                          // block-uniform
  float rnf = RCPF((float)nf);
  float bias = biasv[b];
  const float* pb = inp + (size_t)b * 5 * HW;
  size_t rb = (size_t)b * NREG3 + (size_t)(c - 1) * SREG;
  uint32_t tid = threadIdx.x;

  uint32_t rem[2]; bool act[2];
#pragma unroll
  for (int k = 0; k < 2; ++k) {
    uint32_t slot = bslot + ((uint32_t)k << 8) + tid;
    act[k] = slot < cnt;
    uint32_t sl = act[k] ? slot : (cnt - 1u);  // cnt>=1 here (bslot<cnt)
    rem[k] = remarr[rb + sl];                  // coalesced 4 B
  }

  uint32_t idx[2]; float acc[2];
#pragma unroll
  for (int k = 0; k < 2; ++k) {
    idx[k] = ((uint32_t)b << 22) + rem[k];
    acc[k] = 0.0f;
  }

  if (c == 3) {
    float base2[2], fw2[2], gw2[2], nfa[2], fac[2];
#pragma unroll
    for (int k = 0; k < 2; ++k) {              // gather 4 channels (L2/L3-served)
      uint32_t r = rem[k];
      base2[k] = pb[r] + bias;
      fw2[k] = fmaxf(pb[2 * HW + r], 0.0f);
      float fa = fmaxf(pb[3 * HW + r], 0.0f);
      gw2[k] = fmaxf(pb[4 * HW + r], 0.0f);
      nfa[k] = -fa; fac[k] = fa * 0.52876637294f;
    }
#pragma unroll 2
    for (int f = 0; f < nf; ++f) {             // 2px x 2keys x unroll2 = 8 chains
      uint32_t ub[2], nb[2];
#pragma unroll
      for (int k = 0; k < 2; ++k) ub[k] = rbits32(ku0, ku1, idx[k]);
#pragma unroll
      for (int k = 0; k < 2; ++k) nb[k] = rbits32(kn0, kn1, idx[k]);
#pragma unroll
      for (int k = 0; k < 2; ++k) {
        idx[k] += (uint32_t)HW;
        float u = fminf(fmaxf(unit_from_bits(ub[k]), 1e-6f), 0.999999f);
        float pw = EXP2F(fmaf(nfa[k], LOG2F(-LOG2F(u)), fac[k]));
        float z = sqrt2_erfinv(fmaf(unit_from_bits(nb[k]), 2.0f, -0.99999994f));
        float t = fmaf(gw2[k], z, fmaf(fw2[k], pw, base2[k]));
        acc[k] += fminf(fmaxf(t, 0.0f), 1.0f);
      }
    }
  } else if (c == 1) {
    float base2[2], fw2[2], nfa[2], fac[2];
#pragma unroll
    for (int k = 0; k < 2; ++k) {              // gather 3 channels
      uint32_t r = rem[k];
      base2[k] = pb[r] + bias;
      fw2[k] = fmaxf(pb[2 * HW + r], 0.0f);
      float fa = fmaxf(pb[3 * HW + r], 0.0f);
      nfa[k] = -fa; fac[k] = fa * 0.52876637294f;
    }
#pragma unroll 4
    for (int f = 0; f < nf; ++f) {             // 2px x unroll4 = 8 chains
      uint32_t ub[2];
#pragma unroll
      for (int k = 0; k < 2; ++k) ub[k] = rbits32(ku0, ku1, idx[k]);
#pragma unroll
      for (int k = 0; k < 2; ++k) {
        idx[k] += (uint32_t)HW;
        float u = fminf(fmaxf(unit_from_bits(ub[k]), 1e-6f), 0.999999f);
        float pw = EXP2F(fmaf(nfa[k], LOG2F(-LOG2F(u)), fac[k]));
        acc[k] += fminf(fmaxf(fmaf(fw2[k], pw, base2[k]), 0.0f), 1.0f);
      }
    }
  } else {                                     // c == 2
    float base2[2], gw2[2];
#pragma unroll
    for (int k = 0; k < 2; ++k) {              // gather 2 channels
      uint32_t r = rem[k];
      base2[k] = pb[r] + bias;
      gw2[k] = fmaxf(pb[4 * HW + r], 0.0f);
    }
#pragma unroll 4
    for (int f = 0; f < nf; ++f) {             // 2px x unroll4 = 8 chains
      uint32_t nb[2];
#pragma unroll
      for (int k = 0; k < 2; ++k) nb[k] = rbits32(kn0, kn1, idx[k]);
#pragma unroll
      for (int k = 0; k < 2; ++k) {
        idx[k] += (uint32_t)HW;
        float z = sqrt2_erfinv(fmaf(unit_from_bits(nb[k]), 2.0f, -0.99999994f));
        acc[k] += fminf(fmaxf(fmaf(gw2[k], z, base2[k]), 0.0f), 1.0f);
      }
    }
  }

#pragma unroll
  for (int k = 0; k < 2; ++k)
    if (act[k]) out[(size_t)b * HW + rem[k]] = acc[k] * rnf;
}

// ================= plain tier (proven fallback, batch-major) =================
__global__ __launch_bounds__(256) void bias_partial_plain(const float* __restrict__ inp,
                                                          float* __restrict__ partial) {
  int blk = blockIdx.x;
  int b = blk >> 6, chunk = blk & 63;
  const float4* src = (const float4*)(inp + ((size_t)b * 5 + 1) * HW
                                          + (size_t)chunk * 4096);
  int t = threadIdx.x;
  float s = 0.0f;
#pragma unroll
  for (int k = 0; k < 4; ++k) {
    float4 v = src[t + k * 256];
    s += (v.x + v.y) + (v.z + v.w);
  }
  for (int off = 32; off; off >>= 1) s += __shfl_down(s, off);
  __shared__ float ws4[4];
  if ((t & 63) == 0) ws4[t >> 6] = s;
  __syncthreads();
  if (t == 0) partial[blk] = ws4[0] + ws4[1] + ws4[2] + ws4[3];
}

__global__ __launch_bounds__(256) void acquire_plain(
    const float* __restrict__ inp, const int* __restrict__ frames,
    const float* __restrict__ partial, float* __restrict__ out,
    uint32_t ku0, uint32_t ku1, uint32_t kn0, uint32_t kn1) {
  int b = blockIdx.x >> 10;
  int rem = ((blockIdx.x & 1023) << 8) | threadIdx.x;
  __shared__ float s_bias;
  if (threadIdx.x < 64) {
    float s = partial[(b << 6) | threadIdx.x];
    for (int off = 32; off; off >>= 1) s += __shfl_down(s, off);
    if (threadIdx.x == 0) s_bias = fmaxf(s * (1.0f / 262144.0f), 0.0f);
  }
  const float* pb = inp + (size_t)b * 5 * HW;
  float img = pb[rem];
  float fw  = fmaxf(pb[2 * HW + rem], 0.0f);
  float fa  = fmaxf(pb[3 * HW + rem], 0.0f);
  float gw  = fmaxf(pb[4 * HW + rem], 0.0f);
  __syncthreads();
  float base = img + s_bias;
  int nf = frames[b];
  uint32_t idx = ((uint32_t)b << 22) + (uint32_t)rem;
  float res = loop_fg(base, fw, fa, gw, idx, nf, ku0, ku1, kn0, kn1);
  out[(size_t)b * HW + rem] = res;
  float cpw = EXP2F(-fa * LOG2F(fa + 1.0f));
  out[ACQ_N + (size_t)b * HW + rem] = fminf(fmaxf(fmaf(fw, cpw, base), 0.0f), 1.0f);
}

extern "C" void kernel_launch(void* const* d_in, const int* in_sizes, int n_in,
                              void* d_out, int out_size, void* d_ws, size_t ws_size,
                              hipStream_t stream) {
  const float* inp    = (const float*)d_in[0];
  const int*   frames = (const int*)d_in[1];
  float* out = (float*)d_out;

  // jax_threefry_partitionable=True: split(key(42)) foldlike:
  // ku = cipher((0,42),(0,0)), kn = cipher((0,42),(0,1))
  uint32_t ku0, ku1, kn0, kn1;
  tf2x32_host(0u, 42u, 0u, 0u, ku0, ku1);
  tf2x32_host(0u, 42u, 0u, 1u, kn0, kn1);

  float*    partial  = (float*)d_ws;                     // 512 f32
  float*    biasv    = (float*)((char*)d_ws + 2048);     // 8 f32
  uint32_t* counters = (uint32_t*)((char*)d_ws + 4096);  // 1024 u32 (padded lines)
  const size_t need_full = 8192 + (size_t)8 * NREG3 * 4; // ~6.7 MB

  if (ws_size >= need_full) {
    uint32_t* remarr = (uint32_t*)((char*)d_ws + 8192);
    bias_partial<<<dim3(512), dim3(256), 0, stream>>>(inp, partial, counters);
    scatter_pack<<<dim3(2048), dim3(256), 0, stream>>>(inp, partial, biasv,
                                                       counters, remarr, out);
    acquire_packed<<<dim3(136, 8, 3), dim3(256), 0, stream>>>(inp, frames, biasv,
                                                              counters, remarr, out,
                                                              ku0, ku1, kn0, kn1);
  } else {
    bias_partial_plain<<<dim3(512), dim3(256), 0, stream>>>(inp, partial);
    acquire_plain<<<dim3(8192), dim3(256), 0, stream>>>(inp, frames, partial, out,
                                                        ku0, ku1, kn0, kn1);
  }
}

// Round 13
// 138.587 us; speedup vs baseline: 1.0250x; 1.0250x over previous
//
#include <hip/hip_runtime.h>
#include <stdint.h>

#define HW 262144            // 512*512
#define ACQ_N 2097152        // 8*1*512*512
#define SREG 69632           // slots per class region = 65536 + 4096 slack (18 sigma)
#define NREG3 208896         // 3*SREG slots per batch (classes 1..3)
#define NVCLS 3264           // 3 classes * 8 batches * 136 slot-blocks (512 px each)
#define NVALL 5312           // + 2048 dense center/class0 blocks (1024 px each)

// each (batch,class) counter on its OWN 128-byte line (R3 post-mortem: all
// atomics on one line serialized the whole scatter kernel)
#define CNT(b, c) ((((b) << 2) | (c)) << 5)

// hw-native transcendentals (1 instr each)
#define LOG2F(x) __builtin_amdgcn_logf(x)
#define EXP2F(x) __builtin_amdgcn_exp2f(x)
#define SQRTF(x) __builtin_amdgcn_sqrtf(x)
#define RCPF(x)  __builtin_amdgcn_rcpf(x)

#define ROTL(x, r) __builtin_amdgcn_alignbit((x), (x), (32 - (r)) & 31)

// ---------- host-side threefry2x32 for key derivation ----------
static inline void tf2x32_host(uint32_t k0, uint32_t k1, uint32_t c0, uint32_t c1,
                               uint32_t& o0, uint32_t& o1) {
  const uint32_t ks2 = k0 ^ k1 ^ 0x1BD11BDAu;
  uint32_t x0 = c0 + k0, x1 = c1 + k1;
#define TFR(r) { x0 += x1; x1 = (x1 << (r)) | (x1 >> (32 - (r))); x1 ^= x0; }
  TFR(13) TFR(15) TFR(26) TFR(6)
  x0 += k1;  x1 += ks2 + 1u;
  TFR(17) TFR(29) TFR(16) TFR(24)
  x0 += ks2; x1 += k0 + 2u;
  TFR(13) TFR(15) TFR(26) TFR(6)
  x0 += k0;  x1 += k1 + 3u;
  TFR(17) TFR(29) TFR(16) TFR(24)
  x0 += k1;  x1 += ks2 + 4u;
  TFR(13) TFR(15) TFR(26) TFR(6)
  x0 += ks2; x1 += k0 + 5u;
#undef TFR
  o0 = x0; o1 = x1;
}

// device: partitionable random_bits(32) for counter (0, idx): o0^o1
__device__ __forceinline__ uint32_t rbits32(uint32_t k0, uint32_t k1, uint32_t idx) {
  const uint32_t ks2 = k0 ^ k1 ^ 0x1BD11BDAu;
  uint32_t x0 = k0, x1 = idx + k1;
#define TFR(r) { x0 += x1; x1 = ROTL(x1, r); x1 ^= x0; }
  TFR(13) TFR(15) TFR(26) TFR(6)
  x0 += k1;  x1 += ks2 + 1u;
  TFR(17) TFR(29) TFR(16) TFR(24)
  x0 += ks2; x1 += k0 + 2u;
  TFR(13) TFR(15) TFR(26) TFR(6)
  x0 += k0;  x1 += k1 + 3u;
  TFR(17) TFR(29) TFR(16) TFR(24)
  x0 += k1;  x1 += ks2 + 4u;
  TFR(13) TFR(15) TFR(26) TFR(6)
  x0 += ks2; x1 += k0 + 5u;
#undef TFR
  return x0 ^ x1;
}

__device__ __forceinline__ float unit_from_bits(uint32_t b) {
  return __uint_as_float((b >> 9) | 0x3F800000u) - 1.0f;
}

// z = sqrt(2)*erfinv(x), Giles poly pre-scaled by sqrt(2); far branch real-branched.
__device__ __forceinline__ float sqrt2_erfinv(float x) {
  float ome = fmaf(-x, x, 1.0f);
  float w = -0.69314718056f * LOG2F(ome);
  float wn = w - 2.5f;
  float p = 3.974065e-08f;
  p = fmaf(p, wn, 4.854641e-07f);
  p = fmaf(p, wn, -4.982823e-06f);
  p = fmaf(p, wn, -6.210531e-06f);
  p = fmaf(p, wn, 3.091200e-04f);
  p = fmaf(p, wn, -1.773035e-03f);
  p = fmaf(p, wn, -5.908135e-03f);
  p = fmaf(p, wn, 3.488029e-01f);
  p = fmaf(p, wn, 2.123314e+00f);
  if (__builtin_expect(w >= 5.0f, 0)) {
    float wf = SQRTF(w) - 3.0f;
    float q = -2.831458e-04f;
    q = fmaf(q, wf, 1.427657e-04f);
    q = fmaf(q, wf, 1.908260e-03f);
    q = fmaf(q, wf, -5.195013e-03f);
    q = fmaf(q, wf, 8.116892e-03f);
    q = fmaf(q, wf, -1.0779791e-02f);
    q = fmaf(q, wf, 1.3348579e-02f);
    q = fmaf(q, wf, 1.416582e+00f);
    q = fmaf(q, wf, 4.006434e+00f);
    p = q;
  }
  return p * x;
}

// ---------- 1-pixel loop (plain-tier fallback) ----------
__device__ __forceinline__ float loop_fg(float base, float fw, float fa, float gw,
                                         uint32_t idx, int nf,
                                         uint32_t ku0, uint32_t ku1,
                                         uint32_t kn0, uint32_t kn1) {
  float nfa = -fa, fac = fa * 0.52876637294f;
  float acc = 0.0f;
#pragma unroll 2
  for (int f = 0; f < nf; ++f) {
    uint32_t ub = rbits32(ku0, ku1, idx);
    uint32_t nb = rbits32(kn0, kn1, idx);
    idx += (uint32_t)HW;
    float u = fminf(fmaxf(unit_from_bits(ub), 1e-6f), 0.999999f);
    float pw = EXP2F(fmaf(nfa, LOG2F(-LOG2F(u)), fac));
    float z = sqrt2_erfinv(fmaf(unit_from_bits(nb), 2.0f, -0.99999994f));
    float t = fmaf(gw, z, fmaf(fw, pw, base));
    acc += fminf(fmaxf(t, 0.0f), 1.0f);
  }
  return acc * RCPF((float)nf);
}

// ================= R12: 2-kernel pipeline (ordinary launches) ==============
// R11 post-mortem: hipLaunchCooperativeKernel silently never ran (all-zero
// output) — cooperative launch abandoned. Same fusion benefit re-cut legally:
// classification/remarr need NO bias, so K1 "prep" does bias-partials +
// classify + region-alloc + remarr with no internal dependency; K2
// "acquire_all" covers class regions (heavy, dispatched first) AND the dense
// center/class-0 pass (uniform light blocks, dispatched LAST = drain filler).
// Each K2 block finalizes its batch's bias in-block from partial[] (8KB,
// L2-resident, deterministic fixed tree). One launch boundary removed; the
// center work moves into acquire's drain tail.
// ws: f32 partial[2048] @0 ; u32 counters[1056] @8192 (padded 128B lines,
//     zeroed by hipMemsetAsync) ; u32 remarr[8][NREG3] @16384

__global__ __launch_bounds__(256) void prep(const float* __restrict__ inp,
                                            float* __restrict__ partial,
                                            uint32_t* __restrict__ counters,
                                            uint32_t* __restrict__ remarr) {
  int blk = blockIdx.x;                 // 2048 blocks: 8 batches x 256 subchunks
  int b = blk >> 8, sub = blk & 255;
  int tid = threadIdx.x, lane = tid & 63, wid = tid >> 6;
  const float* pb = inp + (size_t)b * 5 * HW;
  uint64_t below = (1ull << lane) - 1ull;
  int base_i = sub << 10;

  __shared__ float ws4[4];
  __shared__ uint32_t swcnt[4][4];       // [wave][class]
  __shared__ uint32_t sbase[4];

  // bias partial: this block's 1024 floats of channel 1
  {
    const float4* src = (const float4*)(pb + HW + base_i);
    float4 v = src[tid];
    float s = (v.x + v.y) + (v.z + v.w);
    for (int o = 32; o; o >>= 1) s += __shfl_down(s, o);
    if (lane == 0) ws4[wid] = s;
  }

  // classify 4 slices (f2, f4 only), count per wave
  uint32_t cls4[4];
  uint32_t wc1 = 0, wc2 = 0, wc3 = 0;
#pragma unroll
  for (int k = 0; k < 4; ++k) {
    int i = base_i + (k << 8) + tid;
    float f2 = pb[2 * HW + i];
    float f4 = pb[4 * HW + i];
    uint32_t cls = (f2 > 0.0f ? 1u : 0u) | (f4 > 0.0f ? 2u : 0u);
    cls4[k] = cls;
    wc1 += (uint32_t)__popcll(__ballot(cls == 1u));
    wc2 += (uint32_t)__popcll(__ballot(cls == 2u));
    wc3 += (uint32_t)__popcll(__ballot(cls == 3u));
  }
  if (lane == 0) {
    swcnt[wid][1] = wc1; swcnt[wid][2] = wc2; swcnt[wid][3] = wc3;
  }
  __syncthreads();
  if (tid == 0) partial[blk] = ws4[0] + ws4[1] + ws4[2] + ws4[3];
  // 3 atomics per BLOCK, each counter on its own 128B line (R4 recipe)
  if (tid < 3) {
    int c = tid + 1;
    uint32_t tot = swcnt[0][c] + swcnt[1][c] + swcnt[2][c] + swcnt[3][c];
    sbase[c] = atomicAdd(&counters[CNT(b, c)], tot);
  }
  __syncthreads();

  uint32_t run1 = sbase[1], run2 = sbase[2], run3 = sbase[3];
#pragma unroll
  for (int w = 0; w < 4; ++w) {
    if (w < wid) { run1 += swcnt[w][1]; run2 += swcnt[w][2]; run3 += swcnt[w][3]; }
  }

  uint32_t* rbase = remarr + (size_t)b * NREG3;
#pragma unroll
  for (int k = 0; k < 4; ++k) {
    int i = base_i + (k << 8) + tid;
    uint32_t cls = cls4[k];
    uint64_t ba1 = __ballot(cls == 1u);
    uint64_t ba2 = __ballot(cls == 2u);
    uint64_t ba3 = __ballot(cls == 3u);
    if (cls != 0u) {
      uint64_t own  = (cls == 1u) ? ba1 : ((cls == 2u) ? ba2 : ba3);
      uint32_t rbas = (cls == 1u) ? run1 : ((cls == 2u) ? run2 : run3);
      uint32_t roff = (cls - 1u) * (uint32_t)SREG + rbas
                    + (uint32_t)__popcll(own & below);
      rbase[roff] = (uint32_t)i;         // only scattered store (4B/px)
    }
    run1 += (uint32_t)__popcll(ba1);
    run2 += (uint32_t)__popcll(ba2);
    run3 += (uint32_t)__popcll(ba3);
  }
}

// K2: vblocks [0,NVCLS): class regions, class-3 first (R9/R10 proven bodies);
//     vblocks [NVCLS,NVALL): dense center + class-0 pass (drain filler).
__global__ __launch_bounds__(256) void acquire_all(
    const float* __restrict__ inp, const int* __restrict__ frames,
    const float* __restrict__ partial, const uint32_t* __restrict__ counters,
    const uint32_t* __restrict__ remarr, float* __restrict__ out,
    uint32_t ku0, uint32_t ku1, uint32_t kn0, uint32_t kn1) {
  int v = (int)blockIdx.x;
  int tid = threadIdx.x;
  __shared__ float s_bias;

  if (v < NVCLS) {
    int ci = v / 1088;                   // 1088 = 8 batches * 136 slot-blocks
    int c = 3 - ci;                      // class 3, 2, 1 (heavy first globally)
    int r = v - ci * 1088;
    int b = r / 136;
    int sb = r - b * 136;
    uint32_t cnt = counters[CNT(b, c)];
    uint32_t bslot = (uint32_t)sb << 9;  // 512 px per block
    if (bslot >= cnt) return;            // uniform early-out, before barriers

    // bias finalize in-block (deterministic fixed tree; partial[] L2-resident)
    if (tid < 64) {
      int pbase = b << 8;
      float s = partial[pbase + tid] + partial[pbase + tid + 64]
              + partial[pbase + tid + 128] + partial[pbase + tid + 192];
      for (int o = 32; o; o >>= 1) s += __shfl_down(s, o);
      if (tid == 0) s_bias = fmaxf(s * (1.0f / 262144.0f), 0.0f);
    }

    int nf = frames[b];                  // block-uniform
    float rnf = RCPF((float)nf);
    const float* pb = inp + (size_t)b * 5 * HW;
    size_t rb = (size_t)b * NREG3 + (size_t)(c - 1) * SREG;

    uint32_t rem[2]; bool act[2];
#pragma unroll
    for (int k = 0; k < 2; ++k) {
      uint32_t slot = bslot + ((uint32_t)k << 8) + (uint32_t)tid;
      act[k] = slot < cnt;
      uint32_t sl = act[k] ? slot : (cnt - 1u);
      rem[k] = remarr[rb + sl];          // coalesced 4 B
    }
    __syncthreads();
    float bias = s_bias;

    uint32_t idx[2]; float acc[2];
#pragma unroll
    for (int k = 0; k < 2; ++k) {
      idx[k] = ((uint32_t)b << 22) + rem[k];
      acc[k] = 0.0f;
    }

    if (c == 3) {
      float base2[2], fw2[2], gw2[2], nfa[2], fac[2];
#pragma unroll
      for (int k = 0; k < 2; ++k) {      // gather 4 channels (L2/L3-served)
        uint32_t rr = rem[k];
        base2[k] = pb[rr] + bias;
        fw2[k] = fmaxf(pb[2 * HW + rr], 0.0f);
        float fa = fmaxf(pb[3 * HW + rr], 0.0f);
        gw2[k] = fmaxf(pb[4 * HW + rr], 0.0f);
        nfa[k] = -fa; fac[k] = fa * 0.52876637294f;
      }
#pragma unroll 2
      for (int f = 0; f < nf; ++f) {     // 2px x 2keys x unroll2 = 8 chains
        uint32_t ub[2], nb[2];
#pragma unroll
        for (int k = 0; k < 2; ++k) ub[k] = rbits32(ku0, ku1, idx[k]);
#pragma unroll
        for (int k = 0; k < 2; ++k) nb[k] = rbits32(kn0, kn1, idx[k]);
#pragma unroll
        for (int k = 0; k < 2; ++k) {
          idx[k] += (uint32_t)HW;
          float u = fminf(fmaxf(unit_from_bits(ub[k]), 1e-6f), 0.999999f);
          float pw = EXP2F(fmaf(nfa[k], LOG2F(-LOG2F(u)), fac[k]));
          float z = sqrt2_erfinv(fmaf(unit_from_bits(nb[k]), 2.0f, -0.99999994f));
          float t = fmaf(gw2[k], z, fmaf(fw2[k], pw, base2[k]));
          acc[k] += fminf(fmaxf(t, 0.0f), 1.0f);
        }
      }
    } else if (c == 1) {
      float base2[2], fw2[2], nfa[2], fac[2];
#pragma unroll
      for (int k = 0; k < 2; ++k) {      // gather 3 channels
        uint32_t rr = rem[k];
        base2[k] = pb[rr] + bias;
        fw2[k] = fmaxf(pb[2 * HW + rr], 0.0f);
        float fa = fmaxf(pb[3 * HW + rr], 0.0f);
        nfa[k] = -fa; fac[k] = fa * 0.52876637294f;
      }
#pragma unroll 4
      for (int f = 0; f < nf; ++f) {     // 2px x unroll4 = 8 chains
        uint32_t ub[2];
#pragma unroll
        for (int k = 0; k < 2; ++k) ub[k] = rbits32(ku0, ku1, idx[k]);
#pragma unroll
        for (int k = 0; k < 2; ++k) {
          idx[k] += (uint32_t)HW;
          float u = fminf(fmaxf(unit_from_bits(ub[k]), 1e-6f), 0.999999f);
          float pw = EXP2F(fmaf(nfa[k], LOG2F(-LOG2F(u)), fac[k]));
          acc[k] += fminf(fmaxf(fmaf(fw2[k], pw, base2[k]), 0.0f), 1.0f);
        }
      }
    } else {                             // c == 2
      float base2[2], gw2[2];
#pragma unroll
      for (int k = 0; k < 2; ++k) {      // gather 2 channels
        uint32_t rr = rem[k];
        base2[k] = pb[rr] + bias;
        gw2[k] = fmaxf(pb[4 * HW + rr], 0.0f);
      }
#pragma unroll 4
      for (int f = 0; f < nf; ++f) {     // 2px x unroll4 = 8 chains
        uint32_t nb[2];
#pragma unroll
        for (int k = 0; k < 2; ++k) nb[k] = rbits32(kn0, kn1, idx[k]);
#pragma unroll
        for (int k = 0; k < 2; ++k) {
          idx[k] += (uint32_t)HW;
          float z = sqrt2_erfinv(fmaf(unit_from_bits(nb[k]), 2.0f, -0.99999994f));
          acc[k] += fminf(fmaxf(fmaf(gw2[k], z, base2[k]), 0.0f), 1.0f);
        }
      }
    }

#pragma unroll
    for (int k = 0; k < 2; ++k)
      if (act[k]) out[(size_t)b * HW + rem[k]] = acc[k] * rnf;

  } else {
    // ---- dense center + class-0 pass (1024 px per block, coalesced) ----
    int d = v - NVCLS;                   // 0..2047
    int b = d >> 8, sub = d & 255;
    int base_i = sub << 10;
    const float* pb = inp + (size_t)b * 5 * HW;

    if (tid < 64) {
      int pbase = b << 8;
      float s = partial[pbase + tid] + partial[pbase + tid + 64]
              + partial[pbase + tid + 128] + partial[pbase + tid + 192];
      for (int o = 32; o; o >>= 1) s += __shfl_down(s, o);
      if (tid == 0) s_bias = fmaxf(s * (1.0f / 262144.0f), 0.0f);
    }
    __syncthreads();
    float bias = s_bias;

    float* outa = out + (size_t)b * HW;
    float* outc = out + ACQ_N + (size_t)b * HW;
#pragma unroll
    for (int k = 0; k < 4; ++k) {
      int i = base_i + (k << 8) + tid;
      float img = pb[i];
      float f2 = pb[2 * HW + i];
      float f3 = pb[3 * HW + i];
      float f4 = pb[4 * HW + i];
      float fw = fmaxf(f2, 0.0f), fa = fmaxf(f3, 0.0f);
      float basev = img + bias;
      float cpw = EXP2F(-fa * LOG2F(fa + 1.0f));
      float ctr = fminf(fmaxf(fmaf(fw, cpw, basev), 0.0f), 1.0f);
      outc[i] = ctr;
      if (f2 <= 0.0f && f4 <= 0.0f) outa[i] = ctr;   // class 0: acquired==center
    }
  }
}

// ================= plain tier (ws too small) =================
__global__ __launch_bounds__(256) void bias_partial_plain(const float* __restrict__ inp,
                                                          float* __restrict__ partial) {
  int blk = blockIdx.x;
  int b = blk >> 6, chunk = blk & 63;
  const float4* src = (const float4*)(inp + ((size_t)b * 5 + 1) * HW
                                          + (size_t)chunk * 4096);
  int t = threadIdx.x;
  float s = 0.0f;
#pragma unroll
  for (int k = 0; k < 4; ++k) {
    float4 v = src[t + k * 256];
    s += (v.x + v.y) + (v.z + v.w);
  }
  for (int off = 32; off; off >>= 1) s += __shfl_down(s, off);
  __shared__ float ws4[4];
  if ((t & 63) == 0) ws4[t >> 6] = s;
  __syncthreads();
  if (t == 0) partial[blk] = ws4[0] + ws4[1] + ws4[2] + ws4[3];
}

__global__ __launch_bounds__(256) void acquire_plain(
    const float* __restrict__ inp, const int* __restrict__ frames,
    const float* __restrict__ partial, float* __restrict__ out,
    uint32_t ku0, uint32_t ku1, uint32_t kn0, uint32_t kn1) {
  int b = blockIdx.x >> 10;
  int rem = ((blockIdx.x & 1023) << 8) | threadIdx.x;
  __shared__ float s_bias;
  if (threadIdx.x < 64) {
    float s = partial[(b << 6) | threadIdx.x];
    for (int off = 32; off; off >>= 1) s += __shfl_down(s, off);
    if (threadIdx.x == 0) s_bias = fmaxf(s * (1.0f / 262144.0f), 0.0f);
  }
  const float* pb = inp + (size_t)b * 5 * HW;
  float img = pb[rem];
  float fw  = fmaxf(pb[2 * HW + rem], 0.0f);
  float fa  = fmaxf(pb[3 * HW + rem], 0.0f);
  float gw  = fmaxf(pb[4 * HW + rem], 0.0f);
  __syncthreads();
  float base = img + s_bias;
  int nf = frames[b];
  uint32_t idx = ((uint32_t)b << 22) + (uint32_t)rem;
  float res = loop_fg(base, fw, fa, gw, idx, nf, ku0, ku1, kn0, kn1);
  out[(size_t)b * HW + rem] = res;
  float cpw = EXP2F(-fa * LOG2F(fa + 1.0f));
  out[ACQ_N + (size_t)b * HW + rem] = fminf(fmaxf(fmaf(fw, cpw, base), 0.0f), 1.0f);
}

extern "C" void kernel_launch(void* const* d_in, const int* in_sizes, int n_in,
                              void* d_out, int out_size, void* d_ws, size_t ws_size,
                              hipStream_t stream) {
  const float* inp    = (const float*)d_in[0];
  const int*   frames = (const int*)d_in[1];
  float* out = (float*)d_out;

  // jax_threefry_partitionable=True: split(key(42)) foldlike:
  // ku = cipher((0,42),(0,0)), kn = cipher((0,42),(0,1))
  uint32_t ku0, ku1, kn0, kn1;
  tf2x32_host(0u, 42u, 0u, 0u, ku0, ku1);
  tf2x32_host(0u, 42u, 0u, 1u, kn0, kn1);

  float*    partial  = (float*)d_ws;                     // 2048 f32 @0
  uint32_t* counters = (uint32_t*)((char*)d_ws + 8192);  // 1056 u32 (padded lines)
  uint32_t* remarr   = (uint32_t*)((char*)d_ws + 16384); // 8*NREG3 u32
  const size_t need_full = 16384 + (size_t)8 * NREG3 * 4; // ~6.7 MB

  if (ws_size >= need_full) {
    hipMemsetAsync(counters, 0, 1056 * sizeof(uint32_t), stream);
    prep<<<dim3(2048), dim3(256), 0, stream>>>(inp, partial, counters, remarr);
    acquire_all<<<dim3(NVALL), dim3(256), 0, stream>>>(inp, frames, partial,
                                                       counters, remarr, out,
                                                       ku0, ku1, kn0, kn1);
  } else {
    float* partialp = (float*)d_ws;
    bias_partial_plain<<<dim3(512), dim3(256), 0, stream>>>(inp, partialp);
    acquire_plain<<<dim3(8192), dim3(256), 0, stream>>>(inp, frames, partialp, out,
                                                        ku0, ku1, kn0, kn1);
  }
}